// Round 1
// baseline (365.276 us; speedup 1.0000x reference)
//
#include <hip/hip_runtime.h>
#include <stdint.h>

// Attention forward: B=4, H=16, N=2048, D=64, fp32 in/out.
// Flash-style: per block, 64 Q rows; iterate 32 KV tiles of 64 rows.
// bf16 MFMA 16x16x32 for QK^T and PV, fp32 accumulate, online softmax.

#define NSEQ   2048
#define DH     64
#define BM     64      // Q rows per block (16 per wave)
#define BN     64      // KV rows per tile
#define LDS_S  72      // LDS row stride (bf16 elems): 144 B, 16B-aligned, 2-way bank alias (free)
#define NWAVE  4

typedef short bf16x8 __attribute__((ext_vector_type(8)));
typedef float f32x4  __attribute__((ext_vector_type(4)));

__device__ __forceinline__ uint16_t f2bf(float x) {
    // round-to-nearest-even fp32 -> bf16
    uint32_t u = __builtin_bit_cast(uint32_t, x);
    return (uint16_t)((u + 0x7fffu + ((u >> 16) & 1u)) >> 16);
}

__global__ __launch_bounds__(256) void attn_fwd(const float* __restrict__ Qg,
                                                const float* __restrict__ Kg,
                                                const float* __restrict__ Vg,
                                                float* __restrict__ Og) {
    __shared__ short Ks [BN * LDS_S];        // K tile, [j][d] bf16
    __shared__ short Vts[DH * LDS_S];        // V tile transposed, [d][j] bf16
    __shared__ short Ps [NWAVE * 16 * LDS_S];// P tiles, per-wave [row][j] bf16

    const int tid  = threadIdx.x;
    const int wave = tid >> 6;
    const int lane = tid & 63;
    const int quad = lane >> 4;
    const int l16  = lane & 15;

    const int bh = blockIdx.x >> 5;   // 64 batch-heads
    const int qt = blockIdx.x & 31;   // 32 Q tiles

    const size_t base = (size_t)bh * NSEQ * DH;
    const float* Qb = Qg + base;
    const float* Kb = Kg + base;
    const float* Vb = Vg + base;
    float*       Ob = Og + base;

    // ---- load Q fragments (A-layout: m=l16, k=quad*8+j, chunks c=0,1), pre-scaled ----
    const float qscale = 0.125f * 1.44269504f;  // D^-0.5 * log2(e): softmax via exp2
    bf16x8 qfrag[2];
    {
        const int qrow = qt * BM + wave * 16 + l16;
        const float* qp = Qb + (size_t)qrow * DH + quad * 8;
        #pragma unroll
        for (int c = 0; c < 2; ++c) {
            float4 x = *(const float4*)(qp + 32 * c);
            float4 y = *(const float4*)(qp + 32 * c + 4);
            union { uint16_t u[8]; bf16x8 v; } pk;
            pk.u[0] = f2bf(x.x * qscale); pk.u[1] = f2bf(x.y * qscale);
            pk.u[2] = f2bf(x.z * qscale); pk.u[3] = f2bf(x.w * qscale);
            pk.u[4] = f2bf(y.x * qscale); pk.u[5] = f2bf(y.y * qscale);
            pk.u[6] = f2bf(y.z * qscale); pk.u[7] = f2bf(y.w * qscale);
            qfrag[c] = pk.v;
        }
    }

    f32x4 o[4] = {};                 // O accumulator, C-layout: row=quad*4+r, d=n*16+l16
    float m_i[4], l_i[4];
    #pragma unroll
    for (int r = 0; r < 4; ++r) { m_i[r] = -1e30f; l_i[r] = 0.0f; }

    // staging index precompute
    const int kr0 = tid >> 4;          // 0..15 (K row group)
    const int kd0 = (tid & 15) * 4;    // 0..60 (K d offset, float4)
    const int vp  = (tid & 31) * 2;    // V row pair j0
    const int vd0 = (tid >> 5) * 8;    // V d offset (8 floats)

    #pragma unroll 1
    for (int kt = 0; kt < NSEQ / BN; ++kt) {
        __syncthreads();   // previous iteration's LDS reads done before restage

        // ---- stage K tile: global [j][d] fp32 -> LDS [j][d] bf16 (coalesced) ----
        {
            const float* kbase = Kb + (size_t)kt * BN * DH;
            #pragma unroll
            for (int jj = 0; jj < 4; ++jj) {
                const int row = kr0 + jj * 16;
                float4 x = *(const float4*)(kbase + (size_t)row * DH + kd0);
                union { uint16_t u[4]; uint64_t ll; } pk;
                pk.u[0] = f2bf(x.x); pk.u[1] = f2bf(x.y);
                pk.u[2] = f2bf(x.z); pk.u[3] = f2bf(x.w);
                *(uint64_t*)&Ks[row * LDS_S + kd0] = pk.ll;
            }
        }
        // ---- stage V tile transposed: global [j][d] -> LDS Vt[d][j] bf16 ----
        {
            const float* v0 = Vb + (size_t)(kt * BN + vp) * DH + vd0;
            const float* v1 = v0 + DH;
            float4 a0 = *(const float4*)(v0);
            float4 a1 = *(const float4*)(v0 + 4);
            float4 b0 = *(const float4*)(v1);
            float4 b1 = *(const float4*)(v1 + 4);
            float av[8] = {a0.x,a0.y,a0.z,a0.w,a1.x,a1.y,a1.z,a1.w};
            float bv[8] = {b0.x,b0.y,b0.z,b0.w,b1.x,b1.y,b1.z,b1.w};
            #pragma unroll
            for (int i = 0; i < 8; ++i) {
                uint32_t pk = (uint32_t)f2bf(av[i]) | ((uint32_t)f2bf(bv[i]) << 16);
                *(uint32_t*)&Vts[(vd0 + i) * LDS_S + vp] = pk;
            }
        }
        __syncthreads();

        // ---- S = Q K^T (pre-scaled, exp2 domain). C-layout: row=quad*4+r, col j=n*16+l16 ----
        f32x4 s[4] = {};
        #pragma unroll
        for (int c = 0; c < 2; ++c) {
            #pragma unroll
            for (int n = 0; n < 4; ++n) {
                bf16x8 kf = *(const bf16x8*)&Ks[(n * 16 + l16) * LDS_S + quad * 8 + 32 * c];
                s[n] = __builtin_amdgcn_mfma_f32_16x16x32_bf16(qfrag[c], kf, s[n], 0, 0, 0);
            }
        }

        // ---- online softmax over this tile's 64 cols ----
        float rmax[4];
        #pragma unroll
        for (int r = 0; r < 4; ++r)
            rmax[r] = fmaxf(fmaxf(s[0][r], s[1][r]), fmaxf(s[2][r], s[3][r]));
        #pragma unroll
        for (int off = 1; off < 16; off <<= 1) {
            #pragma unroll
            for (int r = 0; r < 4; ++r)
                rmax[r] = fmaxf(rmax[r], __shfl_xor(rmax[r], off, 64));
        }
        float alpha[4], rsum[4];
        #pragma unroll
        for (int r = 0; r < 4; ++r) {
            float mn = fmaxf(m_i[r], rmax[r]);
            alpha[r] = __builtin_amdgcn_exp2f(m_i[r] - mn);
            m_i[r] = mn;
            rsum[r] = 0.0f;
        }
        #pragma unroll
        for (int n = 0; n < 4; ++n) {
            #pragma unroll
            for (int r = 0; r < 4; ++r) {
                float p = __builtin_amdgcn_exp2f(s[n][r] - m_i[r]);
                rsum[r] += p;
                Ps[(wave * 16 + quad * 4 + r) * LDS_S + n * 16 + l16] = (short)f2bf(p);
            }
        }
        #pragma unroll
        for (int off = 1; off < 16; off <<= 1) {
            #pragma unroll
            for (int r = 0; r < 4; ++r)
                rsum[r] += __shfl_xor(rsum[r], off, 64);
        }
        #pragma unroll
        for (int r = 0; r < 4; ++r)
            l_i[r] = l_i[r] * alpha[r] + rsum[r];
        #pragma unroll
        for (int n = 0; n < 4; ++n) {
            #pragma unroll
            for (int r = 0; r < 4; ++r)
                o[n][r] *= alpha[r];
        }

        // ---- O += P V (P via LDS round-trip: C-layout -> A-layout; same-wave, in-order DS) ----
        #pragma unroll
        for (int c = 0; c < 2; ++c) {
            bf16x8 pf = *(const bf16x8*)&Ps[(wave * 16 + l16) * LDS_S + quad * 8 + 32 * c];
            #pragma unroll
            for (int n = 0; n < 4; ++n) {
                bf16x8 vf = *(const bf16x8*)&Vts[(n * 16 + l16) * LDS_S + quad * 8 + 32 * c];
                o[n] = __builtin_amdgcn_mfma_f32_16x16x32_bf16(pf, vf, o[n], 0, 0, 0);
            }
        }
    }

    // ---- epilogue: normalize, store fp32 ----
    float inv[4];
    #pragma unroll
    for (int r = 0; r < 4; ++r) inv[r] = 1.0f / l_i[r];
    const int orow0 = qt * BM + wave * 16 + quad * 4;
    #pragma unroll
    for (int n = 0; n < 4; ++n) {
        #pragma unroll
        for (int r = 0; r < 4; ++r)
            Ob[(size_t)(orow0 + r) * DH + n * 16 + l16] = o[n][r] * inv[r];
    }
}

extern "C" void kernel_launch(void* const* d_in, const int* in_sizes, int n_in,
                              void* d_out, int out_size, void* d_ws, size_t ws_size,
                              hipStream_t stream) {
    (void)in_sizes; (void)n_in; (void)d_ws; (void)ws_size; (void)out_size;
    const float* q = (const float*)d_in[0];
    const float* k = (const float*)d_in[1];
    const float* v = (const float*)d_in[2];
    float* out = (float*)d_out;
    dim3 grid(64 * 32);   // (B*H) * (N/BM)
    dim3 block(256);
    attn_fwd<<<grid, block, 0, stream>>>(q, k, v, out);
}

// Round 2
// 295.844 us; speedup vs baseline: 1.2347x; 1.2347x over previous
//
#include <hip/hip_runtime.h>
#include <stdint.h>

// Attention fwd B=4,H=16,N=2048,D=64 fp32.
// Round 2: prepass converts K->bf16 and V->Vt (transposed, pi-permuted) in ws;
// main kernel: BM=128 (2 waves x m=64), BN=64, mfma_f32_32x32x16_bf16,
// S^T = K*Q^T so exp'd scores feed PV directly from registers (no P LDS trip),
// fixed-max softmax (exp2, deferred l reduction), double-buffered LDS staging.

#define NSEQ 2048
#define DH   64
#define BHN  64        // B*H
#define BM   128
#define BN   64
#define KST  72        // LDS row stride in shorts (144B: 16B-aligned, spreads banks)

typedef short bf16x8 __attribute__((ext_vector_type(8)));
typedef float f32x4  __attribute__((ext_vector_type(4)));
typedef float f32x16 __attribute__((ext_vector_type(16)));

__device__ __forceinline__ uint16_t f2bf(float x) {
    uint32_t u = __builtin_bit_cast(uint32_t, x);
    return (uint16_t)((u + 0x7fffu + ((u >> 16) & 1u)) >> 16);
}
__device__ __forceinline__ uint32_t pk2(float a, float b) {
    return (uint32_t)f2bf(a) | ((uint32_t)f2bf(b) << 16);
}

// ---------------- prepass: K fp32 -> bf16 (same layout) ----------------
__global__ __launch_bounds__(256) void convert_k(const float* __restrict__ K,
                                                 uint16_t* __restrict__ Kb) {
    size_t i = ((size_t)blockIdx.x * 256 + threadIdx.x) * 8;
    float4 a = *(const float4*)(K + i);
    float4 b = *(const float4*)(K + i + 4);
    uint4 o = make_uint4(pk2(a.x, a.y), pk2(a.z, a.w), pk2(b.x, b.y), pk2(b.z, b.w));
    *(uint4*)(Kb + i) = o;
}

// ------- prepass: V [bh][n][d] fp32 -> Vt [bh][d][n] bf16, n pi-permuted -------
// pi within each 16-group: pi16(i) = (i&3) + 8*((i>>2)&1) + 4*((i>>3)&1)
// so that B-frag slot (h,jj) at position 8h+jj supplies V[sigma_h(jj)] matching
// the S^T C-layout register order used as the PV A-operand.
__global__ __launch_bounds__(256) void transpose_v(const float* __restrict__ V,
                                                   uint16_t* __restrict__ Vt) {
    __shared__ uint16_t T[64 * 72];
    const int t  = threadIdx.x;
    const int bh = blockIdx.x >> 5;
    const int n0 = (blockIdx.x & 31) * 64;
    const float* vb = V + (size_t)bh * NSEQ * DH + (size_t)n0 * DH;
    const int n  = t >> 4;
    const int d0 = (t & 15) * 4;
    #pragma unroll
    for (int p = 0; p < 4; ++p) {
        int nn = n + p * 16;
        float4 x = *(const float4*)(vb + nn * DH + d0);
        T[(d0 + 0) * 72 + nn] = f2bf(x.x);
        T[(d0 + 1) * 72 + nn] = f2bf(x.y);
        T[(d0 + 2) * 72 + nn] = f2bf(x.z);
        T[(d0 + 3) * 72 + nn] = f2bf(x.w);
    }
    __syncthreads();
    const int dr = t >> 2;
    const int c0 = (t & 3) * 16;
    uint32_t o[8];
    #pragma unroll
    for (int i2 = 0; i2 < 8; ++i2) {
        int i0 = 2 * i2, i1 = 2 * i2 + 1;
        int s0 = (i0 & 3) + 8 * ((i0 >> 2) & 1) + 4 * ((i0 >> 3) & 1);
        int s1 = (i1 & 3) + 8 * ((i1 >> 2) & 1) + 4 * ((i1 >> 3) & 1);
        o[i2] = (uint32_t)T[dr * 72 + c0 + s0] | ((uint32_t)T[dr * 72 + c0 + s1] << 16);
    }
    uint16_t* out = Vt + ((size_t)bh * DH + dr) * NSEQ + n0 + c0;
    *(uint4*)(out)     = make_uint4(o[0], o[1], o[2], o[3]);
    *(uint4*)(out + 8) = make_uint4(o[4], o[5], o[6], o[7]);
}

// ---------------- main kernel ----------------
__global__ __launch_bounds__(128, 2) void attn_main(const float* __restrict__ Qg,
                                                    const uint16_t* __restrict__ Kb,
                                                    const uint16_t* __restrict__ Vt,
                                                    float* __restrict__ Og) {
    __shared__ __align__(16) uint16_t Ks[2][BN * KST];
    __shared__ __align__(16) uint16_t Vs[2][DH * KST];
    __shared__ float Lb[BM];

    const int tid  = threadIdx.x;
    const int w    = tid >> 6;
    const int lane = tid & 63;
    const int l31  = lane & 31;
    const int h    = lane >> 5;

    const int bh = blockIdx.x >> 4;
    const int qt = blockIdx.x & 15;

    const float qscale = 0.125f * 1.44269504f;  // D^-0.5 * log2(e)

    // Q fragments (B-operand of S^T = K*Q^T): frag (nt,kt):
    // lane: n = i = qt*128 + w*64 + nt*32 + l31 ; k = d = kt*16 + h*8 + jj
    bf16x8 qf[2][4];
    #pragma unroll
    for (int nt = 0; nt < 2; ++nt) {
        const float* qp = Qg + ((size_t)bh * NSEQ + (size_t)(qt * BM + w * 64 + nt * 32 + l31)) * DH + h * 8;
        #pragma unroll
        for (int kt = 0; kt < 4; ++kt) {
            float4 a = *(const float4*)(qp + kt * 16);
            float4 b = *(const float4*)(qp + kt * 16 + 4);
            union { uint32_t u[4]; bf16x8 v; } pk;
            pk.u[0] = pk2(a.x * qscale, a.y * qscale);
            pk.u[1] = pk2(a.z * qscale, a.w * qscale);
            pk.u[2] = pk2(b.x * qscale, b.y * qscale);
            pk.u[3] = pk2(b.z * qscale, b.w * qscale);
            qf[nt][kt] = pk.v;
        }
    }

    f32x16 oacc[2][2] = {};      // O C-tiles: [nt=i-tile][nd=d-tile]
    float lsum[2] = {0.0f, 0.0f};

    const uint16_t* Kbase = Kb + (size_t)bh * NSEQ * DH;
    const uint16_t* Vbase = Vt + (size_t)bh * DH * NSEQ;

    uint4 kr[4], vr[4];
    // pipeline: load kt -> regs ; store regs -> LDS[kt&1] one iter later
    {
        #pragma unroll
        for (int i = 0; i < 4; ++i) {
            int C = i * 128 + tid, r = C >> 3, p = C & 7;
            kr[i] = *(const uint4*)(Kbase + (size_t)(0 * BN + r) * DH + p * 8);
            vr[i] = *(const uint4*)(Vbase + (size_t)r * NSEQ + 0 * BN + p * 8);
        }
        #pragma unroll
        for (int i = 0; i < 4; ++i) {
            int C = i * 128 + tid, r = C >> 3, p = C & 7;
            *(uint4*)&Ks[0][r * KST + p * 8] = kr[i];
            *(uint4*)&Vs[0][r * KST + p * 8] = vr[i];
        }
        #pragma unroll
        for (int i = 0; i < 4; ++i) {
            int C = i * 128 + tid, r = C >> 3, p = C & 7;
            kr[i] = *(const uint4*)(Kbase + (size_t)(1 * BN + r) * DH + p * 8);
            vr[i] = *(const uint4*)(Vbase + (size_t)r * NSEQ + 1 * BN + p * 8);
        }
    }

    #pragma unroll 1
    for (int kt = 0; kt < NSEQ / BN; ++kt) {
        const int cur = kt & 1;
        __syncthreads();
        if (kt + 1 < NSEQ / BN) {   // store prefetched tile kt+1
            #pragma unroll
            for (int i = 0; i < 4; ++i) {
                int C = i * 128 + tid, r = C >> 3, p = C & 7;
                *(uint4*)&Ks[cur ^ 1][r * KST + p * 8] = kr[i];
                *(uint4*)&Vs[cur ^ 1][r * KST + p * 8] = vr[i];
            }
        }
        if (kt + 2 < NSEQ / BN) {   // prefetch tile kt+2 into regs (async)
            #pragma unroll
            for (int i = 0; i < 4; ++i) {
                int C = i * 128 + tid, r = C >> 3, p = C & 7;
                kr[i] = *(const uint4*)(Kbase + (size_t)((kt + 2) * BN + r) * DH + p * 8);
                vr[i] = *(const uint4*)(Vbase + (size_t)r * NSEQ + (kt + 2) * BN + p * 8);
            }
        }

        // ---- compute on LDS[cur] ----
        #pragma unroll
        for (int mtj = 0; mtj < 2; ++mtj) {
            bf16x8 kf[4];        // A-operand: K rows j = kt*64 + mtj*32 + l31
            #pragma unroll
            for (int k2 = 0; k2 < 4; ++k2)
                kf[k2] = *(const bf16x8*)&Ks[cur][(mtj * 32 + l31) * KST + k2 * 16 + h * 8];
            bf16x8 vfl[2][2];    // B-operand for PV: ktg = 2*mtj + ktl
            #pragma unroll
            for (int ktl = 0; ktl < 2; ++ktl)
                #pragma unroll
                for (int nd = 0; nd < 2; ++nd)
                    vfl[ktl][nd] = *(const bf16x8*)&Vs[cur][(nd * 32 + l31) * KST + (2 * mtj + ktl) * 16 + h * 8];

            #pragma unroll
            for (int nt = 0; nt < 2; ++nt) {
                f32x16 s = {};
                #pragma unroll
                for (int k2 = 0; k2 < 4; ++k2)
                    s = __builtin_amdgcn_mfma_f32_32x32x16_bf16(kf[k2], qf[nt][k2], s, 0, 0, 0);
                // p = exp2(s); S^T C-regs [8*ktl + jj] are exactly PV A-frag slot order
                bf16x8 pf[2];
                float ls = 0.0f;
                #pragma unroll
                for (int ktl = 0; ktl < 2; ++ktl) {
                    union { uint32_t u[4]; bf16x8 v; } pp;
                    #pragma unroll
                    for (int t2 = 0; t2 < 4; ++t2) {
                        float e0 = __builtin_amdgcn_exp2f(s[ktl * 8 + 2 * t2]);
                        float e1 = __builtin_amdgcn_exp2f(s[ktl * 8 + 2 * t2 + 1]);
                        ls += e0 + e1;
                        pp.u[t2] = pk2(e0, e1);
                    }
                    pf[ktl] = pp.v;
                }
                lsum[nt] += ls;
                #pragma unroll
                for (int nd = 0; nd < 2; ++nd) {
                    oacc[nt][nd] = __builtin_amdgcn_mfma_f32_32x32x16_bf16(pf[0], vfl[0][nd], oacc[nt][nd], 0, 0, 0);
                    oacc[nt][nd] = __builtin_amdgcn_mfma_f32_32x32x16_bf16(pf[1], vfl[1][nd], oacc[nt][nd], 0, 0, 0);
                }
            }
        }
    }

    // ---- epilogue: combine l over lane halves, exchange via LDS, normalize ----
    lsum[0] += __shfl_xor(lsum[0], 32);
    lsum[1] += __shfl_xor(lsum[1], 32);
    if (h == 0) {
        Lb[w * 64 + l31]      = lsum[0];
        Lb[w * 64 + 32 + l31] = lsum[1];
    }
    // same-wave DS ordering makes Lb visible to this wave without a barrier
    float* Ob = Og + (size_t)bh * NSEQ * DH;
    #pragma unroll
    for (int nt = 0; nt < 2; ++nt) {
        float inv[16];
        #pragma unroll
        for (int rg = 0; rg < 16; ++rg) {
            int il = (rg & 3) + 8 * (rg >> 2) + 4 * h;
            inv[rg] = 1.0f / Lb[w * 64 + nt * 32 + il];
        }
        #pragma unroll
        for (int nd = 0; nd < 2; ++nd)
            #pragma unroll
            for (int rg = 0; rg < 16; ++rg) {
                int il  = (rg & 3) + 8 * (rg >> 2) + 4 * h;
                int row = qt * BM + w * 64 + nt * 32 + il;
                Ob[(size_t)row * DH + nd * 32 + l31] = oacc[nt][nd][rg] * inv[rg];
            }
    }
}

// ---------------- fallback (round-1 kernel, used if ws too small) ----------------
#define LDS_S 72
#define NWAVE 4
__global__ __launch_bounds__(256) void attn_fwd_fb(const float* __restrict__ Qg,
                                                   const float* __restrict__ Kg,
                                                   const float* __restrict__ Vg,
                                                   float* __restrict__ Og) {
    __shared__ short KsF[BN * LDS_S];
    __shared__ short VtsF[DH * LDS_S];
    __shared__ short PsF[NWAVE * 16 * LDS_S];
    const int tid = threadIdx.x;
    const int wave = tid >> 6, lane = tid & 63, quad = lane >> 4, l16 = lane & 15;
    const int bh = blockIdx.x >> 5, qtf = blockIdx.x & 31;
    const size_t base = (size_t)bh * NSEQ * DH;
    const float* Qb = Qg + base; const float* Kbf = Kg + base;
    const float* Vb = Vg + base; float* Ob = Og + base;
    const float qscale = 0.125f * 1.44269504f;
    bf16x8 qfrag[2];
    {
        const int qrow = qtf * 64 + wave * 16 + l16;
        const float* qp = Qb + (size_t)qrow * DH + quad * 8;
        #pragma unroll
        for (int c = 0; c < 2; ++c) {
            float4 x = *(const float4*)(qp + 32 * c);
            float4 y = *(const float4*)(qp + 32 * c + 4);
            union { uint16_t u[8]; bf16x8 v; } pk;
            pk.u[0]=f2bf(x.x*qscale); pk.u[1]=f2bf(x.y*qscale);
            pk.u[2]=f2bf(x.z*qscale); pk.u[3]=f2bf(x.w*qscale);
            pk.u[4]=f2bf(y.x*qscale); pk.u[5]=f2bf(y.y*qscale);
            pk.u[6]=f2bf(y.z*qscale); pk.u[7]=f2bf(y.w*qscale);
            qfrag[c] = pk.v;
        }
    }
    f32x4 o[4] = {};
    float m_i[4], l_i[4];
    #pragma unroll
    for (int r = 0; r < 4; ++r) { m_i[r] = -1e30f; l_i[r] = 0.0f; }
    const int kr0 = tid >> 4, kd0 = (tid & 15) * 4;
    const int vp = (tid & 31) * 2, vd0 = (tid >> 5) * 8;
    #pragma unroll 1
    for (int kt = 0; kt < NSEQ / BN; ++kt) {
        __syncthreads();
        {
            const float* kbase = Kbf + (size_t)kt * BN * DH;
            #pragma unroll
            for (int jj = 0; jj < 4; ++jj) {
                const int row = kr0 + jj * 16;
                float4 x = *(const float4*)(kbase + (size_t)row * DH + kd0);
                union { uint16_t u[4]; uint64_t ll; } pk;
                pk.u[0]=f2bf(x.x); pk.u[1]=f2bf(x.y); pk.u[2]=f2bf(x.z); pk.u[3]=f2bf(x.w);
                *(uint64_t*)&KsF[row * LDS_S + kd0] = pk.ll;
            }
        }
        {
            const float* v0 = Vb + (size_t)(kt * BN + vp) * DH + vd0;
            const float* v1 = v0 + DH;
            float4 a0 = *(const float4*)(v0); float4 a1 = *(const float4*)(v0 + 4);
            float4 b0 = *(const float4*)(v1); float4 b1 = *(const float4*)(v1 + 4);
            float av[8] = {a0.x,a0.y,a0.z,a0.w,a1.x,a1.y,a1.z,a1.w};
            float bv[8] = {b0.x,b0.y,b0.z,b0.w,b1.x,b1.y,b1.z,b1.w};
            #pragma unroll
            for (int i = 0; i < 8; ++i)
                *(uint32_t*)&VtsF[(vd0 + i) * LDS_S + vp] = pk2(av[i], bv[i]);
        }
        __syncthreads();
        f32x4 s[4] = {};
        #pragma unroll
        for (int c = 0; c < 2; ++c)
            #pragma unroll
            for (int n = 0; n < 4; ++n) {
                bf16x8 kfr = *(const bf16x8*)&KsF[(n * 16 + l16) * LDS_S + quad * 8 + 32 * c];
                s[n] = __builtin_amdgcn_mfma_f32_16x16x32_bf16(qfrag[c], kfr, s[n], 0, 0, 0);
            }
        float rmax[4];
        #pragma unroll
        for (int r = 0; r < 4; ++r)
            rmax[r] = fmaxf(fmaxf(s[0][r], s[1][r]), fmaxf(s[2][r], s[3][r]));
        #pragma unroll
        for (int off = 1; off < 16; off <<= 1)
            #pragma unroll
            for (int r = 0; r < 4; ++r)
                rmax[r] = fmaxf(rmax[r], __shfl_xor(rmax[r], off, 64));
        float alpha[4], rsum[4];
        #pragma unroll
        for (int r = 0; r < 4; ++r) {
            float mn = fmaxf(m_i[r], rmax[r]);
            alpha[r] = __builtin_amdgcn_exp2f(m_i[r] - mn);
            m_i[r] = mn; rsum[r] = 0.0f;
        }
        #pragma unroll
        for (int n = 0; n < 4; ++n)
            #pragma unroll
            for (int r = 0; r < 4; ++r) {
                float p = __builtin_amdgcn_exp2f(s[n][r] - m_i[r]);
                rsum[r] += p;
                PsF[(wave * 16 + quad * 4 + r) * LDS_S + n * 16 + l16] = (short)f2bf(p);
            }
        #pragma unroll
        for (int off = 1; off < 16; off <<= 1)
            #pragma unroll
            for (int r = 0; r < 4; ++r)
                rsum[r] += __shfl_xor(rsum[r], off, 64);
        #pragma unroll
        for (int r = 0; r < 4; ++r) l_i[r] = l_i[r] * alpha[r] + rsum[r];
        #pragma unroll
        for (int n = 0; n < 4; ++n)
            #pragma unroll
            for (int r = 0; r < 4; ++r) o[n][r] *= alpha[r];
        #pragma unroll
        for (int c = 0; c < 2; ++c) {
            bf16x8 pfr = *(const bf16x8*)&PsF[(wave * 16 + l16) * LDS_S + quad * 8 + 32 * c];
            #pragma unroll
            for (int n = 0; n < 4; ++n) {
                bf16x8 vfr = *(const bf16x8*)&VtsF[(n * 16 + l16) * LDS_S + quad * 8 + 32 * c];
                o[n] = __builtin_amdgcn_mfma_f32_16x16x32_bf16(pfr, vfr, o[n], 0, 0, 0);
            }
        }
    }
    float inv[4];
    #pragma unroll
    for (int r = 0; r < 4; ++r) inv[r] = 1.0f / l_i[r];
    const int orow0 = qtf * 64 + wave * 16 + quad * 4;
    #pragma unroll
    for (int n = 0; n < 4; ++n)
        #pragma unroll
        for (int r = 0; r < 4; ++r)
            Ob[(size_t)(orow0 + r) * DH + n * 16 + l16] = o[n][r] * inv[r];
}

extern "C" void kernel_launch(void* const* d_in, const int* in_sizes, int n_in,
                              void* d_out, int out_size, void* d_ws, size_t ws_size,
                              hipStream_t stream) {
    (void)in_sizes; (void)n_in; (void)out_size;
    const float* q = (const float*)d_in[0];
    const float* k = (const float*)d_in[1];
    const float* v = (const float*)d_in[2];
    float* out = (float*)d_out;
    const size_t elems = (size_t)BHN * NSEQ * DH;     // 8.39M per tensor
    const size_t need  = 2 * elems * sizeof(uint16_t); // 33.6 MB
    if (ws_size >= need) {
        uint16_t* kb = (uint16_t*)d_ws;
        uint16_t* vt = kb + elems;
        convert_k<<<dim3(elems / 8 / 256), dim3(256), 0, stream>>>(k, kb);
        transpose_v<<<dim3(BHN * (NSEQ / 64)), dim3(256), 0, stream>>>(v, vt);
        attn_main<<<dim3(BHN * (NSEQ / BM)), dim3(128), 0, stream>>>(q, kb, vt, out);
    } else {
        attn_fwd_fb<<<dim3(BHN * (NSEQ / 64)), dim3(256), 0, stream>>>(q, k, v, out);
    }
}

// Round 3
// 224.366 us; speedup vs baseline: 1.6280x; 1.3186x over previous
//
#include <hip/hip_runtime.h>
#include <stdint.h>

// Attention fwd B=4,H=16,N=2048,D=64 fp32.
// Round 3: single merged prepass (K->bf16, V->Vt bf16 transposed+pi-permuted);
// main: BM=256 (4 waves x 64 Q rows), BN=64, mfma_f32_32x32x16_bf16,
// S^T = K*Q^T (exp'd scores feed PV directly from regs), fixed-max softmax,
// K/V staged via global_load_lds(16B) with XOR-swizzled LDS layout (no spills).

#define NSEQ 2048
#define DH   64
#define BHN  64
#define BM   256
#define BN   64

typedef short bf16x8 __attribute__((ext_vector_type(8)));
typedef float f32x4  __attribute__((ext_vector_type(4)));
typedef float f32x16 __attribute__((ext_vector_type(16)));

__device__ __forceinline__ uint16_t f2bf(float x) {
    uint32_t u = __builtin_bit_cast(uint32_t, x);
    return (uint16_t)((u + 0x7fffu + ((u >> 16) & 1u)) >> 16);
}
__device__ __forceinline__ uint32_t pk2(float a, float b) {
    return (uint32_t)f2bf(a) | ((uint32_t)f2bf(b) << 16);
}
__device__ __forceinline__ void gload_lds16(const uint16_t* g, uint16_t* l) {
    __builtin_amdgcn_global_load_lds(
        (const __attribute__((address_space(1))) uint32_t*)g,
        (__attribute__((address_space(3))) uint32_t*)l, 16, 0, 0);
}

// ---------------- merged prepass ----------------
// blocks [0,4096): K fp32 -> bf16 (same layout), 8 elems/thread.
// blocks [4096,6144): V [bh][n][d] -> Vt [bh][d][n] bf16, n pi-permuted per 16-group:
//   out pos i <- src (i&3) + 8*((i>>2)&1) + 4*((i>>3)&1)   (round-2 verified)
__global__ __launch_bounds__(256) void prepass(const float* __restrict__ K,
                                               const float* __restrict__ V,
                                               uint16_t* __restrict__ Kb,
                                               uint16_t* __restrict__ Vt) {
    __shared__ float T[64 * 68];   // stride 68 floats: conflict-free stage
    int b = blockIdx.x;
    if (b < 4096) {
        size_t i = ((size_t)b * 256 + threadIdx.x) * 8;
        float4 a = *(const float4*)(K + i);
        float4 c = *(const float4*)(K + i + 4);
        *(uint4*)(Kb + i) = make_uint4(pk2(a.x, a.y), pk2(a.z, a.w),
                                       pk2(c.x, c.y), pk2(c.z, c.w));
        return;
    }
    b -= 4096;
    const int t  = threadIdx.x;
    const int bh = b >> 5;
    const int n0 = (b & 31) * 64;
    const float* vb = V + (size_t)bh * NSEQ * DH + (size_t)n0 * DH;
    {
        const int n = t >> 4, d0 = (t & 15) * 4;
        #pragma unroll
        for (int p = 0; p < 4; ++p)
            *(float4*)&T[(n + 16 * p) * 68 + d0] =
                *(const float4*)(vb + (size_t)(n + 16 * p) * DH + d0);
    }
    __syncthreads();
    const int d = t >> 2;
    #pragma unroll
    for (int q = 0; q < 2; ++q) {
        const int oct = (t & 3) + 4 * q;
        const int g = oct >> 1, ib = (oct & 1) * 8;
        float f[8];
        #pragma unroll
        for (int j = 0; j < 8; ++j) {
            int i = ib + j;
            int s = (i & 3) + 8 * ((i >> 2) & 1) + 4 * ((i >> 3) & 1);
            f[j] = T[(g * 16 + s) * 68 + d];
        }
        uint4 o = make_uint4(pk2(f[0], f[1]), pk2(f[2], f[3]),
                             pk2(f[4], f[5]), pk2(f[6], f[7]));
        *(uint4*)(Vt + ((size_t)bh * DH + d) * NSEQ + n0 + oct * 8) = o;
    }
}

// ---------------- main kernel ----------------
// LDS tile layout (K and V identical): 64 rows x 128 B; logical 16B chunk c of
// row r stored at physical chunk c ^ (r&7)  -> conflict-free b128 frag reads
// AND lane-ordered staging compatible with global_load_lds (swizzle applied to
// the per-lane GLOBAL source address instead of the LDS address).
__global__ __launch_bounds__(256) void attn_main(const float* __restrict__ Qg,
                                                 const uint16_t* __restrict__ Kb,
                                                 const uint16_t* __restrict__ Vt,
                                                 float* __restrict__ Og) {
    __shared__ __align__(16) uint16_t Ks[BN * DH];   // 8 KB
    __shared__ __align__(16) uint16_t Vs[DH * BN];   // 8 KB
    __shared__ float Lb[BM];

    const int tid = threadIdx.x;
    const int w = tid >> 6, lane = tid & 63, l31 = lane & 31, h = lane >> 5;
    const int bh = blockIdx.x >> 3;
    const int qt = blockIdx.x & 7;

    // Q fragments (B-operand of S^T = K*Q^T), pre-scaled into exp2 domain
    const float qscale = 0.125f * 1.44269504f;
    bf16x8 qf[2][4];
    #pragma unroll
    for (int nt = 0; nt < 2; ++nt) {
        const float* qp = Qg + ((size_t)bh * NSEQ +
                                (size_t)(qt * BM + w * 64 + nt * 32 + l31)) * DH + h * 8;
        #pragma unroll
        for (int k2 = 0; k2 < 4; ++k2) {
            float4 a = *(const float4*)(qp + k2 * 16);
            float4 c = *(const float4*)(qp + k2 * 16 + 4);
            union { uint32_t u[4]; bf16x8 v; } pk;
            pk.u[0] = pk2(a.x * qscale, a.y * qscale);
            pk.u[1] = pk2(a.z * qscale, a.w * qscale);
            pk.u[2] = pk2(c.x * qscale, c.y * qscale);
            pk.u[3] = pk2(c.z * qscale, c.w * qscale);
            qf[nt][k2] = pk.v;
        }
    }

    f32x16 oacc[2][2] = {};
    float lsum[2] = {0.0f, 0.0f};

    // staging: wave w owns slots {2w, 2w+1}; each slot = 8 rows = 1 KB per issue
    const int rr = w * 16 + (lane >> 3);        // row for slot 2w (slot 2w+1: +8)
    const int cc = (lane & 7) ^ (lane >> 3);    // logical chunk (XOR swizzle)
    const uint16_t* gK = Kb + (size_t)bh * NSEQ * DH + (size_t)rr * DH + cc * 8;
    const uint16_t* gV = Vt + (size_t)bh * DH * NSEQ + (size_t)rr * NSEQ + cc * 8;
    uint16_t* lK = &Ks[w * 1024];
    uint16_t* lV = &Vs[w * 1024];

    #pragma unroll 1
    for (int kt = 0; kt < NSEQ / BN; ++kt) {
        __syncthreads();                         // prior compute done: LDS reusable
        gload_lds16(gK,            lK);
        gload_lds16(gK + 8 * DH,   lK + 512);
        gload_lds16(gV,            lV);
        gload_lds16(gV + 8 * NSEQ, lV + 512);
        gK += BN * DH;
        gV += BN;
        __syncthreads();                         // vmcnt drained: tile ready

        #pragma unroll
        for (int mtj = 0; mtj < 2; ++mtj) {
            bf16x8 kf[4];                        // A: K rows j = kt*64+mtj*32+l31
            #pragma unroll
            for (int k2 = 0; k2 < 4; ++k2) {
                int row = mtj * 32 + l31, c = k2 * 2 + h;
                kf[k2] = *(const bf16x8*)&Ks[row * 64 + (c ^ (row & 7)) * 8];
            }
            bf16x8 vfl[2][2];                    // B for PV
            #pragma unroll
            for (int ktl = 0; ktl < 2; ++ktl)
                #pragma unroll
                for (int nd = 0; nd < 2; ++nd) {
                    int row = nd * 32 + l31, c = (2 * mtj + ktl) * 2 + h;
                    vfl[ktl][nd] = *(const bf16x8*)&Vs[row * 64 + (c ^ (row & 7)) * 8];
                }
            #pragma unroll
            for (int nt = 0; nt < 2; ++nt) {
                f32x16 s = {};
                #pragma unroll
                for (int k2 = 0; k2 < 4; ++k2)
                    s = __builtin_amdgcn_mfma_f32_32x32x16_bf16(kf[k2], qf[nt][k2], s, 0, 0, 0);
                // p = exp2(s); S^T C-regs [8*ktl+jj] are PV A-frag slot order.
                // Pack by truncation: one v_perm per pair (bias ~2^-9, in budget).
                bf16x8 pf[2];
                float ls = 0.0f;
                #pragma unroll
                for (int ktl = 0; ktl < 2; ++ktl) {
                    union { uint32_t u[4]; bf16x8 v; } pp;
                    #pragma unroll
                    for (int t2 = 0; t2 < 4; ++t2) {
                        float e0 = __builtin_amdgcn_exp2f(s[ktl * 8 + 2 * t2]);
                        float e1 = __builtin_amdgcn_exp2f(s[ktl * 8 + 2 * t2 + 1]);
                        ls += e0 + e1;
                        pp.u[t2] = __builtin_amdgcn_perm(
                            __builtin_bit_cast(uint32_t, e1),
                            __builtin_bit_cast(uint32_t, e0), 0x07060302u);
                    }
                    pf[ktl] = pp.v;
                }
                lsum[nt] += ls;
                #pragma unroll
                for (int nd = 0; nd < 2; ++nd) {
                    oacc[nt][nd] = __builtin_amdgcn_mfma_f32_32x32x16_bf16(pf[0], vfl[0][nd], oacc[nt][nd], 0, 0, 0);
                    oacc[nt][nd] = __builtin_amdgcn_mfma_f32_32x32x16_bf16(pf[1], vfl[1][nd], oacc[nt][nd], 0, 0, 0);
                }
            }
        }
    }

    // epilogue: fold lane halves, exchange via LDS (same-wave), normalize
    lsum[0] += __shfl_xor(lsum[0], 32);
    lsum[1] += __shfl_xor(lsum[1], 32);
    if (h == 0) {
        Lb[w * 64 + l31]      = lsum[0];
        Lb[w * 64 + 32 + l31] = lsum[1];
    }
    float* Ob = Og + (size_t)bh * NSEQ * DH;
    #pragma unroll
    for (int nt = 0; nt < 2; ++nt) {
        float inv[16];
        #pragma unroll
        for (int rg = 0; rg < 16; ++rg) {
            int il = (rg & 3) + 8 * (rg >> 2) + 4 * h;
            inv[rg] = 1.0f / Lb[w * 64 + nt * 32 + il];
        }
        #pragma unroll
        for (int nd = 0; nd < 2; ++nd)
            #pragma unroll
            for (int rg = 0; rg < 16; ++rg) {
                int il  = (rg & 3) + 8 * (rg >> 2) + 4 * h;
                int row = qt * BM + w * 64 + nt * 32 + il;
                Ob[(size_t)row * DH + nd * 32 + l31] = oacc[nt][nd][rg] * inv[rg];
            }
    }
}

// ---------------- fallback (round-1 kernel, if ws too small) ----------------
#define LDS_S 72
#define NWAVE 4
__global__ __launch_bounds__(256) void attn_fwd_fb(const float* __restrict__ Qg,
                                                   const float* __restrict__ Kg,
                                                   const float* __restrict__ Vg,
                                                   float* __restrict__ Og) {
    __shared__ short KsF[BN * LDS_S];
    __shared__ short VtsF[DH * LDS_S];
    __shared__ short PsF[NWAVE * 16 * LDS_S];
    const int tid = threadIdx.x;
    const int wave = tid >> 6, lane = tid & 63, quad = lane >> 4, l16 = lane & 15;
    const int bh = blockIdx.x >> 5, qtf = blockIdx.x & 31;
    const size_t base = (size_t)bh * NSEQ * DH;
    const float* Qb = Qg + base; const float* Kbf = Kg + base;
    const float* Vb = Vg + base; float* Ob = Og + base;
    const float qscale = 0.125f * 1.44269504f;
    bf16x8 qfrag[2];
    {
        const int qrow = qtf * 64 + wave * 16 + l16;
        const float* qp = Qb + (size_t)qrow * DH + quad * 8;
        #pragma unroll
        for (int c = 0; c < 2; ++c) {
            float4 x = *(const float4*)(qp + 32 * c);
            float4 y = *(const float4*)(qp + 32 * c + 4);
            union { uint16_t u[8]; bf16x8 v; } pk;
            pk.u[0]=f2bf(x.x*qscale); pk.u[1]=f2bf(x.y*qscale);
            pk.u[2]=f2bf(x.z*qscale); pk.u[3]=f2bf(x.w*qscale);
            pk.u[4]=f2bf(y.x*qscale); pk.u[5]=f2bf(y.y*qscale);
            pk.u[6]=f2bf(y.z*qscale); pk.u[7]=f2bf(y.w*qscale);
            qfrag[c] = pk.v;
        }
    }
    f32x4 o[4] = {};
    float m_i[4], l_i[4];
    #pragma unroll
    for (int r = 0; r < 4; ++r) { m_i[r] = -1e30f; l_i[r] = 0.0f; }
    const int kr0 = tid >> 4, kd0 = (tid & 15) * 4;
    const int vp = (tid & 31) * 2, vd0 = (tid >> 5) * 8;
    #pragma unroll 1
    for (int kt = 0; kt < NSEQ / BN; ++kt) {
        __syncthreads();
        {
            const float* kbase = Kbf + (size_t)kt * BN * DH;
            #pragma unroll
            for (int jj = 0; jj < 4; ++jj) {
                const int row = kr0 + jj * 16;
                float4 x = *(const float4*)(kbase + (size_t)row * DH + kd0);
                union { uint16_t u[4]; uint64_t ll; } pk;
                pk.u[0]=f2bf(x.x); pk.u[1]=f2bf(x.y); pk.u[2]=f2bf(x.z); pk.u[3]=f2bf(x.w);
                *(uint64_t*)&KsF[row * LDS_S + kd0] = pk.ll;
            }
        }
        {
            const float* v0 = Vb + (size_t)(kt * BN + vp) * DH + vd0;
            const float* v1 = v0 + DH;
            float4 a0 = *(const float4*)(v0); float4 a1 = *(const float4*)(v0 + 4);
            float4 b0 = *(const float4*)(v1); float4 b1 = *(const float4*)(v1 + 4);
            float av[8] = {a0.x,a0.y,a0.z,a0.w,a1.x,a1.y,a1.z,a1.w};
            float bv[8] = {b0.x,b0.y,b0.z,b0.w,b1.x,b1.y,b1.z,b1.w};
            #pragma unroll
            for (int i = 0; i < 8; ++i)
                *(uint32_t*)&VtsF[(vd0 + i) * LDS_S + vp] = pk2(av[i], bv[i]);
        }
        __syncthreads();
        f32x4 s[4] = {};
        #pragma unroll
        for (int c = 0; c < 2; ++c)
            #pragma unroll
            for (int n = 0; n < 4; ++n) {
                bf16x8 kfr = *(const bf16x8*)&KsF[(n * 16 + l16) * LDS_S + quad * 8 + 32 * c];
                s[n] = __builtin_amdgcn_mfma_f32_16x16x32_bf16(qfrag[c], kfr, s[n], 0, 0, 0);
            }
        float rmax[4];
        #pragma unroll
        for (int r = 0; r < 4; ++r)
            rmax[r] = fmaxf(fmaxf(s[0][r], s[1][r]), fmaxf(s[2][r], s[3][r]));
        #pragma unroll
        for (int off = 1; off < 16; off <<= 1)
            #pragma unroll
            for (int r = 0; r < 4; ++r)
                rmax[r] = fmaxf(rmax[r], __shfl_xor(rmax[r], off, 64));
        float alpha[4], rsum[4];
        #pragma unroll
        for (int r = 0; r < 4; ++r) {
            float mn = fmaxf(m_i[r], rmax[r]);
            alpha[r] = __builtin_amdgcn_exp2f(m_i[r] - mn);
            m_i[r] = mn; rsum[r] = 0.0f;
        }
        #pragma unroll
        for (int n = 0; n < 4; ++n)
            #pragma unroll
            for (int r = 0; r < 4; ++r) {
                float p = __builtin_amdgcn_exp2f(s[n][r] - m_i[r]);
                rsum[r] += p;
                PsF[(wave * 16 + quad * 4 + r) * LDS_S + n * 16 + l16] = (short)f2bf(p);
            }
        #pragma unroll
        for (int off = 1; off < 16; off <<= 1)
            #pragma unroll
            for (int r = 0; r < 4; ++r)
                rsum[r] += __shfl_xor(rsum[r], off, 64);
        #pragma unroll
        for (int r = 0; r < 4; ++r) l_i[r] = l_i[r] * alpha[r] + rsum[r];
        #pragma unroll
        for (int n = 0; n < 4; ++n)
            #pragma unroll
            for (int r = 0; r < 4; ++r) o[n][r] *= alpha[r];
        #pragma unroll
        for (int c = 0; c < 2; ++c) {
            bf16x8 pfr = *(const bf16x8*)&PsF[(wave * 16 + l16) * LDS_S + quad * 8 + 32 * c];
            #pragma unroll
            for (int n = 0; n < 4; ++n) {
                bf16x8 vfr = *(const bf16x8*)&VtsF[(n * 16 + l16) * LDS_S + quad * 8 + 32 * c];
                o[n] = __builtin_amdgcn_mfma_f32_16x16x32_bf16(pfr, vfr, o[n], 0, 0, 0);
            }
        }
    }
    float inv[4];
    #pragma unroll
    for (int r = 0; r < 4; ++r) inv[r] = 1.0f / l_i[r];
    const int orow0 = qtf * 64 + wave * 16 + quad * 4;
    #pragma unroll
    for (int n = 0; n < 4; ++n)
        #pragma unroll
        for (int r = 0; r < 4; ++r)
            Ob[(size_t)(orow0 + r) * DH + n * 16 + l16] = o[n][r] * inv[r];
}

extern "C" void kernel_launch(void* const* d_in, const int* in_sizes, int n_in,
                              void* d_out, int out_size, void* d_ws, size_t ws_size,
                              hipStream_t stream) {
    (void)in_sizes; (void)n_in; (void)out_size;
    const float* q = (const float*)d_in[0];
    const float* k = (const float*)d_in[1];
    const float* v = (const float*)d_in[2];
    float* out = (float*)d_out;
    const size_t elems = (size_t)BHN * NSEQ * DH;
    const size_t need  = 2 * elems * sizeof(uint16_t);   // 33.6 MB
    if (ws_size >= need) {
        uint16_t* kb = (uint16_t*)d_ws;
        uint16_t* vt = kb + elems;
        prepass<<<dim3(4096 + BHN * (NSEQ / 64)), dim3(256), 0, stream>>>(k, v, kb, vt);
        attn_main<<<dim3(BHN * (NSEQ / BM)), dim3(256), 0, stream>>>(q, kb, vt, out);
    } else {
        attn_fwd_fb<<<dim3(BHN * (NSEQ / 64)), dim3(256), 0, stream>>>(q, k, v, out);
    }
}